// Round 10
// baseline (339.718 us; speedup 1.0000x reference)
//
#include <hip/hip_runtime.h>

typedef __attribute__((ext_vector_type(8))) short short8;
typedef __attribute__((ext_vector_type(8))) unsigned short ushort8;
typedef __attribute__((ext_vector_type(4))) unsigned short us4;
typedef __attribute__((ext_vector_type(4))) float f32x4;
typedef __attribute__((ext_vector_type(4))) int i32x4;

#define S_LEN 2048
#define D_MODEL 1024
#define N_HEADS 16
#define HEAD_DIM 64

__device__ __forceinline__ unsigned short f2bf(float f) {
  union { float f; unsigned u; } x; x.f = f;
  unsigned r = x.u + 0x7FFFu + ((x.u >> 16) & 1u);
  return (unsigned short)(r >> 16);
}

// pack two f32 -> bf16 pair in ONE VALU op (RNE rounding)
__device__ __forceinline__ int cvtpk(float a, float b) {
  int r;
  asm("v_cvt_pk_bf16_f32 %0, %1, %2" : "=v"(r) : "v"(a), "v"(b));
  return r;
}

// ---------- all 4 weights: W [K][N] fp32 -> Wt [N][K] bf16, one dispatch ----------
__global__ __launch_bounds__(256) void transpose_w4(
    const float* __restrict__ Wq, const float* __restrict__ Wk,
    const float* __restrict__ Wv, const float* __restrict__ Wo,
    unsigned short* __restrict__ wqkvT, unsigned short* __restrict__ woT) {
  __shared__ float tile[64][65];
  const int z = blockIdx.z;
  const float* W = (z == 0) ? Wq : (z == 1) ? Wk : (z == 2) ? Wv : Wo;
  unsigned short* Wt = (z < 3) ? (wqkvT + (size_t)z * D_MODEL * D_MODEL) : woT;
  const int no = blockIdx.x * 64, ko = blockIdx.y * 64;
  const int tx = threadIdx.x & 63, ty = threadIdx.x >> 6;
  for (int r = ty; r < 64; r += 4)
    tile[r][tx] = W[(size_t)(ko + r) * D_MODEL + no + tx];
  __syncthreads();
  for (int r = ty; r < 64; r += 4)
    Wt[(size_t)(no + r) * D_MODEL + ko + tx] = f2bf(tile[tx][r]);
}

// ---------- bf16 GEMM, BK=32, tri-buffered ----------
// MODE0 (fused QKV): A is the ORIGINAL fp32 q/k/v -- no bf16 pre-pass. A staged
// via reg path: {2x global dwordx4 -> 4x v_cvt_pk_bf16_f32 -> ds_write_b128},
// producing byte-identical LDS layout to the old global_load_lds staging.
// T14 split: loads for tile kt+3 issue at tile kt; ds_write at tile kt+1
// (~3500cyc flight >> HBM latency). Wait-chain: writeA(kt+2)'s compiler-inserted
// vmcnt (reg-load deps, issued AFTER stageB(kt+2)) transitively drains B(kt+1)
// before the end-of-tile barrier -> manual counted vmcnt gone except kt==30 tail.
// MODE1 (out proj): unchanged R8 structure (bf16 gload_lds A, counted vmcnt).
template <int MODE>
__global__ __launch_bounds__(256, (MODE == 0 ? 2 : 3)) void proj_gemm(
    const void* __restrict__ A0v, const void* __restrict__ A1v,
    const void* __restrict__ A2v,
    const unsigned short* __restrict__ Bt,
    const float* __restrict__ b0p, const float* __restrict__ b1p,
    const float* __restrict__ b2p,
    void* __restrict__ o0, void* __restrict__ o1, void* __restrict__ o2,
    float qscale) {
  constexpr int NJ = (MODE == 0) ? 8 : 4;        // B-frags per wave
  constexpr int BN = NJ * 32;                    // block N (256 / 128)
  constexpr int BUFS = 4096 + NJ * 1024;         // shorts per buffer (12288 / 8192)
  constexpr int NBI = NJ / 2;                    // B stage instrs (4 / 2)
  extern __shared__ __align__(16) unsigned short smem_d[];  // 3 * BUFS shorts
  const int tid = threadIdx.x;
  const int wave = tid >> 6, lane = tid & 63;
  const int quad = lane >> 4, l16 = lane & 15;

  // bijective XCD remap
  const int GX = (MODE == 0) ? 12 : 8;
  const int nlin = blockIdx.y * GX + blockIdx.x;
  const int xcd = nlin & 7;
  const int j = nlin >> 3;  // MODE0: 0..95, MODE1: 0..63
  int bx_eff, by_eff;
  if (MODE == 0) { by_eff = xcd * 8 + j / 12; bx_eff = j % 12; }
  else           { by_eff = xcd * 8 + (j >> 3); bx_eff = j & 7; }
  const int m0 = by_eff * 128, n0 = bx_eff * BN;
  const int wm = (wave >> 1) * 64, wn = (wave & 1) * (NJ * 16);

  const int sel = (MODE == 0) ? (n0 >> 10) : 0;
  const void* Av = (MODE == 0) ? (sel == 0 ? A0v : sel == 1 ? A1v : A2v) : A0v;
  const float* bias = (MODE == 0) ? (sel == 0 ? b0p : sel == 1 ? b1p : b2p) : b0p;
  const float scale = (MODE == 0 && sel == 0) ? qscale : 1.0f;
  const int nb = (MODE == 0) ? (n0 & 1023) : n0;

  f32x4 acc[4][NJ] = {};

  // staging geometry (shared): lane l covers row base+(l>>2), stored slot l&3;
  // logical chunk there = (l&3) ^ ((row>>1)&3) = (l&3) ^ ((l>>3)&3).
  const int lrow = lane >> 2;
  const int kcs = ((lane & 3) ^ ((lane >> 3) & 3)) << 3;  // element offset

  auto stageB = [&](int kt, int bsel) {
    unsigned short* Bb = smem_d + bsel * BUFS + 4096;
    const int k0 = kt * 32;
#pragma unroll
    for (int c = 0; c < NBI; ++c) {
      const int r = wave * (BN / 4) + c * 16;
      const unsigned short* gb = Bt + (size_t)(n0 + r + lrow) * D_MODEL + k0 + kcs;
      __builtin_amdgcn_global_load_lds((const __attribute__((address_space(1))) void*)gb,
          (__attribute__((address_space(3))) void*)(Bb + r * 32), 16, 0, 0);
    }
  };

  // MODE0: fp32 A reg-staging (load / write split)
  f32x4 ald[4];
  auto loadA = [&](int kt) {
    const float* Af = (const float*)Av;
    const int k0 = kt * 32;
#pragma unroll
    for (int c = 0; c < 2; ++c) {
      const float* ga = Af + (size_t)(m0 + wave * 32 + c * 16 + lrow) * D_MODEL + k0 + kcs;
      ald[2 * c] = *(const f32x4*)ga;
      ald[2 * c + 1] = *(const f32x4*)(ga + 4);
    }
  };
  auto writeA = [&](int bsel) {
    unsigned short* Ab = smem_d + bsel * BUFS;
#pragma unroll
    for (int c = 0; c < 2; ++c) {
      i32x4 w;
      w[0] = cvtpk(ald[2 * c][0], ald[2 * c][1]);
      w[1] = cvtpk(ald[2 * c][2], ald[2 * c][3]);
      w[2] = cvtpk(ald[2 * c + 1][0], ald[2 * c + 1][1]);
      w[3] = cvtpk(ald[2 * c + 1][2], ald[2 * c + 1][3]);
      *(i32x4*)(Ab + (wave * 32 + c * 16) * 32 + lane * 8) = w;
    }
  };

  // MODE1: bf16 A via global_load_lds (R8-verified)
  auto stageA1 = [&](int kt, int bsel) {
    unsigned short* Ab = smem_d + bsel * BUFS;
    const int k0 = kt * 32;
#pragma unroll
    for (int c = 0; c < 2; ++c) {
      const int r = wave * 32 + c * 16;
      const unsigned short* ga = (const unsigned short*)Av +
          (size_t)(m0 + r + lrow) * D_MODEL + k0 + kcs;
      __builtin_amdgcn_global_load_lds((const __attribute__((address_space(1))) void*)ga,
          (__attribute__((address_space(3))) void*)(Ab + r * 32), 16, 0, 0);
    }
  };

  // frag read slot: quad ^ ((l16>>1)&3)  (R6-verified conflict-free swizzle)
  const int fsw = (quad ^ ((l16 >> 1) & 3)) << 3;

  // prologue: tiles 0,1,2 fully staged and drained
  if constexpr (MODE == 0) {
    for (int t = 0; t < 3; ++t) { loadA(t); writeA(t); stageB(t, t); }
    asm volatile("s_waitcnt lgkmcnt(0)" ::: "memory");
    asm volatile("s_waitcnt vmcnt(0)" ::: "memory");
  } else {
    stageA1(0, 0); stageB(0, 0);
    stageA1(1, 1); stageB(1, 1);
    stageA1(2, 2); stageB(2, 2);
    asm volatile("s_waitcnt vmcnt(8)" ::: "memory");
  }
  __builtin_amdgcn_s_barrier();
  __builtin_amdgcn_sched_barrier(0);

  for (int kt = 0; kt < 32; ++kt) {
    const int bsel = kt % 3;
    const unsigned short* Ab = smem_d + bsel * BUFS;
    const unsigned short* Bb = Ab + 4096;
    short8 af[4], bf[NJ];
#pragma unroll
    for (int i = 0; i < 4; ++i)
      af[i] = *(const short8*)(Ab + (wm + i * 16 + l16) * 32 + fsw);
#pragma unroll
    for (int j2 = 0; j2 < NJ; ++j2)
      bf[j2] = *(const short8*)(Bb + (wn + j2 * 16 + l16) * 32 + fsw);
    asm volatile("s_waitcnt lgkmcnt(0)" ::: "memory");
    __builtin_amdgcn_s_barrier();   // all waves' reads of tile kt complete
    __builtin_amdgcn_sched_barrier(0);
    if constexpr (MODE == 0) {
      // write A(kt+2) from regs loaded last iteration (buf (kt+2)%3 = (kt-1)%3,
      // its reads retired at tile kt-1's mid barrier)
      if (kt >= 1 && kt + 2 < 32) writeA((kt + 2) % 3);
      // issue next stage: B FIRST so writeA's implied vmcnt next iter drains it
      if (kt + 3 < 32) { stageB(kt + 3, bsel); loadA(kt + 3); }
    } else {
      if (kt + 3 < 32) { stageA1(kt + 3, bsel); stageB(kt + 3, bsel); }
    }
    __builtin_amdgcn_s_setprio(1);
#pragma unroll
    for (int i = 0; i < 4; ++i)
#pragma unroll
      for (int j2 = 0; j2 < NJ; ++j2)
        acc[i][j2] = __builtin_amdgcn_mfma_f32_16x16x32_bf16(af[i], bf[j2], acc[i][j2], 0, 0, 0);
    __builtin_amdgcn_s_setprio(0);
    if constexpr (MODE == 0) {
      // steady state: writeA's dep-wait already drained B(kt+1); tail only
      if (kt == 30) { asm volatile("s_waitcnt vmcnt(0)" ::: "memory"); }
    } else {
      if (kt + 3 < 32)      { asm volatile("s_waitcnt vmcnt(8)" ::: "memory"); }
      else if (kt + 2 < 32) { asm volatile("s_waitcnt vmcnt(4)" ::: "memory"); }
      else if (kt + 1 < 32) { asm volatile("s_waitcnt vmcnt(0)" ::: "memory"); }
    }
    __builtin_amdgcn_s_barrier();   // publish tile kt+1
    __builtin_amdgcn_sched_barrier(0);
  }

  float bv[NJ];
#pragma unroll
  for (int j2 = 0; j2 < NJ; ++j2) bv[j2] = bias[nb + wn + j2 * 16 + l16];

  if constexpr (MODE == 0) {
    if (sel < 2) {
      unsigned short* T = smem_d + wave * 2176;
      unsigned short* out = (unsigned short*)(sel == 0 ? o0 : o1);
      const int h0 = (nb + wn) >> 6;
#pragma unroll
      for (int i = 0; i < 4; ++i) {
#pragma unroll
        for (int j2 = 0; j2 < 8; ++j2)
#pragma unroll
          for (int r = 0; r < 4; ++r)
            T[(quad * 4 + r) * 136 + j2 * 16 + l16] = f2bf((acc[i][j2][r] + bv[j2]) * scale);
        int m = m0 + wm + i * 16 + l16;
        int b = m >> 11, s = m & 2047;
#pragma unroll
        for (int t = 0; t < 4; ++t) {
          short8 row = *(const short8*)(T + l16 * 136 + t * 32 + quad * 8);
          int c = t * 32 + quad * 8;
          int h = h0 + (c >> 6), d = c & 63;
          *(short8*)(out + (((size_t)(b * N_HEADS + h) * S_LEN + s) << 6) + d) = row;
        }
      }
    } else {
      unsigned short* vt = (unsigned short*)o2;
#pragma unroll
      for (int i = 0; i < 4; ++i) {
        int m = m0 + wm + i * 16 + quad * 4;
        int b = m >> 11, s = m & 2047;
#pragma unroll
        for (int j2 = 0; j2 < 8; ++j2) {
          int n = nb + wn + j2 * 16 + l16;
          int h = n >> 6, d = n & 63;
          us4 pv;
#pragma unroll
          for (int r = 0; r < 4; ++r) pv[r] = f2bf(acc[i][j2][r] + bv[j2]);
          *(us4*)(vt + (((size_t)(b * N_HEADS + h) * 64 + d) << 11) + s) = pv;
        }
      }
    }
  } else {
    float* Tf = (float*)smem_d + wave * 1088;
    float* out = (float*)o0;
#pragma unroll
    for (int i = 0; i < 4; ++i) {
#pragma unroll
      for (int j2 = 0; j2 < 4; ++j2)
#pragma unroll
        for (int r = 0; r < 4; ++r)
          Tf[(quad * 4 + r) * 68 + j2 * 16 + l16] = acc[i][j2][r] + bv[j2];
      int m = m0 + wm + i * 16 + l16;
#pragma unroll
      for (int t = 0; t < 4; ++t) {
        f32x4 row = *(const f32x4*)(Tf + l16 * 68 + t * 16 + quad * 4);
        *(f32x4*)(out + (size_t)m * D_MODEL + nb + wn + t * 16 + quad * 4) = row;
      }
    }
  }
}

// ---------- causal flash attention: PAIR-blocks (p, 15-p) share one K/V stream ----------
// R9-verified: pair-block owns q-strips p*128.. AND (15-p)*128.. with one shared
// K/V stream; durations near-uniform -> causal tail gone; K/V reads feed 4 strips.
__global__ __launch_bounds__(256, 2) void flash_attn(
    const unsigned short* __restrict__ Qh,  // [B,H,S,64] bf16 (scaled)
    const unsigned short* __restrict__ Kh,  // [B,H,S,64] bf16
    const unsigned short* __restrict__ Vt,  // [B,H,64,S] bf16
    unsigned short* __restrict__ ctx) {     // [B,S,1024] bf16
  __shared__ __align__(16) unsigned short smem[16384];  // 32 KB: 2 x (K 8KB | V 8KB)
  const int tid = threadIdx.x;
  const int wave = tid >> 6, lane = tid & 63;
  const int quad = lane >> 4, l16 = lane & 15;
  const int l7 = l16 & 7;

  const int nlin = blockIdx.y * 8 + blockIdx.x;  // 0..511
  const int xcd = nlin & 7;
  const int rr = nlin >> 3;            // 0..63
  const int lo = rr & 31, hi = rr >> 5;
  const int hg = lo >> 2;
  const int pp = (lo & 3) + hi * 4;    // 0..7
  const int p = (pp < 4) ? pp : 11 - pp;  // {0,1,2,3,7,6,5,4}
  const int bh = xcd * 8 + hg;
  const int q0A = p * 128, q0B = (15 - p) * 128;
  const int nkA = 2 * p + 2, nkB = 32 - 2 * p;   // nkA <= 16 < 18 <= nkB
  const size_t hb = (size_t)bh * (S_LEN * HEAD_DIM);
  const int srow = lane >> 3;
  const int schunk = ((lane & 7) ^ srow) * 8;

  auto stage = [&](int kt, int buf) {
    unsigned short* Kb = smem + buf * 8192;
    unsigned short* Vb = smem + buf * 8192 + 4096;
#pragma unroll
    for (int c = 0; c < 2; ++c) {
      int row = wave * 16 + c * 8 + srow;
      const unsigned short* gk = Kh + hb + (size_t)(kt * 64 + row) * 64 + schunk;
      __builtin_amdgcn_global_load_lds((const __attribute__((address_space(1))) void*)gk,
          (__attribute__((address_space(3))) void*)(Kb + (wave * 16 + c * 8) * 64), 16, 0, 0);
      const unsigned short* gv = Vt + hb + (size_t)row * S_LEN + kt * 64 + schunk;
      __builtin_amdgcn_global_load_lds((const __attribute__((address_space(1))) void*)gv,
          (__attribute__((address_space(3))) void*)(Vb + (wave * 16 + c * 8) * 64), 16, 0, 0);
    }
  };

  stage(0, 0);

  short8 qf[4][2];
#pragma unroll
  for (int s = 0; s < 4; ++s) {
    const int q0 = (s < 2) ? q0A : q0B;
#pragma unroll
    for (int t = 0; t < 2; ++t)
      qf[s][t] = *(const short8*)(Qh + hb +
          (size_t)(q0 + wave * 32 + (s & 1) * 16 + l16) * 64 + t * 32 + quad * 8);
  }

  f32x4 o[4][4] = {};  // o[ntd][s]
  float rsum[4] = {0.f, 0.f, 0.f, 0.f};

  for (int kt = 0; kt < nkB; ++kt) {
    __syncthreads();
    if (kt + 1 < nkB) stage(kt + 1, (kt + 1) & 1);
    const unsigned short* Kb = smem + (kt & 1) * 8192;
    const unsigned short* Vb = Kb + 4096;

    const bool actA = (kt * 64 <= q0A + wave * 32 + 31);

    int pk[4][4][2];
#pragma unroll
    for (int nt = 0; nt < 4; ++nt) {
      short8 k0 = *(const short8*)(Kb + (nt * 16 + l16) * 64 + ((quad ^ l7) << 3));
      short8 k1 = *(const short8*)(Kb + (nt * 16 + l16) * 64 + (((4 + quad) ^ l7) << 3));
#pragma unroll
      for (int s = 0; s < 4; ++s) {
        if (s < 2 && !actA) continue;
        f32x4 z = {};
        z = __builtin_amdgcn_mfma_f32_16x16x32_bf16(k0, qf[s][0], z, 0, 0, 0);
        z = __builtin_amdgcn_mfma_f32_16x16x32_bf16(k1, qf[s][1], z, 0, 0, 0);
        const int dstart = (s < 2) ? (nkA - 2) : (nkB - 2);
        if (kt >= dstart) {
          const int qg = ((s < 2) ? q0A : q0B) + wave * 32 + (s & 1) * 16 + l16;
          const int kg = kt * 64 + nt * 16 + quad * 4;
#pragma unroll
          for (int r = 0; r < 4; ++r)
            if (kg + r > qg) z[r] = -1e30f;
        }
        float p0 = __builtin_amdgcn_exp2f(z[0]);
        float p1 = __builtin_amdgcn_exp2f(z[1]);
        float p2 = __builtin_amdgcn_exp2f(z[2]);
        float p3 = __builtin_amdgcn_exp2f(z[3]);
        rsum[s] += (p0 + p1) + (p2 + p3);
        pk[s][nt][0] = cvtpk(p0, p1);
        pk[s][nt][1] = cvtpk(p2, p3);
      }
    }

    union { int i[4]; short8 v; } pf[4][2];
#pragma unroll
    for (int s = 0; s < 4; ++s) {
      if (s < 2 && !actA) continue;
#pragma unroll
      for (int t = 0; t < 2; ++t) {
        int A = pk[s][t * 2][0], C = pk[s][t * 2 + 1][0];
        int B2 = pk[s][t * 2][1], D = pk[s][t * 2 + 1][1];
        asm("v_permlane32_swap_b32 %0, %1" : "+v"(A), "+v"(C));
        asm("v_permlane16_swap_b32 %0, %1" : "+v"(A), "+v"(C));
        asm("v_permlane32_swap_b32 %0, %1" : "+v"(B2), "+v"(D));
        asm("v_permlane16_swap_b32 %0, %1" : "+v"(B2), "+v"(D));
        pf[s][t].i[0] = A;
        pf[s][t].i[1] = B2;
        pf[s][t].i[2] = C;
        pf[s][t].i[3] = D;
      }
    }

    __builtin_amdgcn_s_setprio(1);
#pragma unroll
    for (int ntd = 0; ntd < 4; ++ntd) {
      short8 v0 = *(const short8*)(Vb + (ntd * 16 + l16) * 64 + ((quad ^ l7) << 3));
      short8 v1 = *(const short8*)(Vb + (ntd * 16 + l16) * 64 + (((4 + quad) ^ l7) << 3));
#pragma unroll
      for (int s = 0; s < 4; ++s) {
        if (s < 2 && !actA) continue;
        o[ntd][s] = __builtin_amdgcn_mfma_f32_16x16x32_bf16(v0, pf[s][0].v, o[ntd][s], 0, 0, 0);
        o[ntd][s] = __builtin_amdgcn_mfma_f32_16x16x32_bf16(v1, pf[s][1].v, o[ntd][s], 0, 0, 0);
      }
    }
    __builtin_amdgcn_s_setprio(0);
  }

#pragma unroll
  for (int s = 0; s < 4; ++s) {
    rsum[s] += __shfl_xor(rsum[s], 16, 64);
    rsum[s] += __shfl_xor(rsum[s], 32, 64);
  }

  const int b = bh >> 4, h = bh & 15;
  unsigned short* Os = smem;  // [128 q][72]
#pragma unroll
  for (int qb = 0; qb < 2; ++qb) {
    __syncthreads();
#pragma unroll
    for (int s2 = 0; s2 < 2; ++s2) {
      const int s = qb * 2 + s2;
      float invl = 1.0f / rsum[s];
#pragma unroll
      for (int ntd = 0; ntd < 4; ++ntd) {
        us4 pk4;
#pragma unroll
        for (int r = 0; r < 4; ++r) pk4[r] = f2bf(o[ntd][s][r] * invl);
        *(us4*)(Os + (wave * 32 + s2 * 16 + l16) * 72 + ntd * 16 + quad * 4) = pk4;
      }
    }
    __syncthreads();
    const int q0 = qb ? q0B : q0A;
#pragma unroll
    for (int it = 0; it < 4; ++it) {
      int e = it * 256 + tid;
      int row = e >> 3, c = (e & 7) * 8;
      short8 vrow = *(const short8*)(Os + row * 72 + c);
      *(short8*)(ctx + (size_t)(b * S_LEN + q0 + row) * D_MODEL + h * HEAD_DIM + c) = vrow;
    }
  }
}

// ---------- launch ----------
extern "C" void kernel_launch(void* const* d_in, const int* in_sizes, int n_in,
                              void* d_out, int out_size, void* d_ws, size_t ws_size,
                              hipStream_t stream) {
  (void)in_sizes; (void)n_in; (void)out_size;
  const float* q  = (const float*)d_in[0];
  const float* k  = (const float*)d_in[1];
  const float* v  = (const float*)d_in[2];
  const float* Wq = (const float*)d_in[4];
  const float* bq = (const float*)d_in[5];
  const float* Wk = (const float*)d_in[6];
  const float* bk = (const float*)d_in[7];
  const float* Wv = (const float*)d_in[8];
  const float* bv = (const float*)d_in[9];
  const float* Wo = (const float*)d_in[10];
  const float* bo = (const float*)d_in[11];
  float* out = (float*)d_out;

  if (ws_size < 109051904u) return;
  char* ws = (char*)d_ws;
  unsigned short* ctx   = (unsigned short*)(ws);             // [B,S,1024] bf16
  unsigned short* wqkvT = (unsigned short*)(ws + 50331648);  // [3072][1024] = 6 MB
  unsigned short* woT   = (unsigned short*)(ws + 56623104);
  unsigned short* qh    = (unsigned short*)(ws + 58720256);
  unsigned short* kh    = qh + 8388608;
  unsigned short* vt    = kh + 8388608;  // [B,H,64,S] written directly by proj<0>

  static int attr_done = 0;
  if (!attr_done) {
    auto* k0f = proj_gemm<0>;
    auto* k1f = proj_gemm<1>;
    hipFuncSetAttribute(reinterpret_cast<const void*>(k0f),
                        hipFuncAttributeMaxDynamicSharedMemorySize, 73728);
    hipFuncSetAttribute(reinterpret_cast<const void*>(k1f),
                        hipFuncAttributeMaxDynamicSharedMemorySize, 49152);
    attr_done = 1;
  }

  transpose_w4<<<dim3(16, 16, 4), 256, 0, stream>>>(Wq, Wk, Wv, Wo, wqkvT, woT);
  // fused QKV projection straight from fp32 q/k/v; Q scale folds 1/sqrt(64), log2(e)
  proj_gemm<0><<<dim3(12, 64), 256, 73728, stream>>>(q, k, v, wqkvT, bq, bk, bv,
                                                     qh, kh, vt, 0.125f * 1.44269504088896f);
  flash_attn<<<dim3(8, 64), 256, 0, stream>>>(qh, kh, vt, ctx);
  proj_gemm<1><<<dim3(8, 64), 256, 49152, stream>>>(ctx, ctx, ctx, woT, bo, bo, bo,
                                                    out, out, out, 1.0f);
}